// Round 4
// baseline (255.944 us; speedup 1.0000x reference)
//
#include <hip/hip_runtime.h>

#define N_SEQ 8192
#define HDIM  128

typedef _Float16 half8v  __attribute__((ext_vector_type(8)));
typedef float    floatx16 __attribute__((ext_vector_type(16)));
typedef unsigned int uint32;

// ---------------------------------------------------------------------------
// prep_kv: one block per 32-key tile. Stages K and V fp32 tiles in LDS, then
// writes f16 fragments in EXACT mfma operand order, lane-major, so fa_main's
// fragment loads are fully coalesced 1KB wave loads.
//   K16s[((nt*8 + kc)*64 + lane)*8 + j]  = K[nt*32 + l31][kc*16 + q5*8 + j]
//   Vs[(((nt*4+dt)*2+kc2)*64 + lane)*8+j]= V[nt*32 + kc2*16+q5*8+j][dt*32+l31]
// ---------------------------------------------------------------------------
__global__ void prep_kv(const float* __restrict__ K, const float* __restrict__ V,
                        _Float16* __restrict__ K16s, _Float16* __restrict__ Vs) {
    __shared__ float Kl[32 * 132];
    __shared__ float Vl[32 * 132];
    const int t  = threadIdx.x;
    const int nt = blockIdx.x;
    const int n0 = nt * 32;
    #pragma unroll
    for (int kk = 0; kk < 4; kk++) {
        int idx = t + 256 * kk;                      // 1024 float4s = 32x128
        int nl = idx >> 5, c4 = idx & 31;
        float4 f = *(((const float4*)(K + (size_t)(n0 + nl) * HDIM)) + c4);
        float* dk = &Kl[nl * 132 + c4 * 4];
        dk[0] = f.x; dk[1] = f.y; dk[2] = f.z; dk[3] = f.w;
        float4 g = *(((const float4*)(V + (size_t)(n0 + nl) * HDIM)) + c4);
        float* dv = &Vl[nl * 132 + c4 * 4];
        dv[0] = g.x; dv[1] = g.y; dv[2] = g.z; dv[3] = g.w;
    }
    __syncthreads();
    #pragma unroll
    for (int rep = 0; rep < 2; rep++) {              // 512 K chunks
        int ch = t + rep * 256;
        int kc = ch >> 6, lane = ch & 63, l31 = lane & 31, q5 = (lane >> 5) & 1;
        half8v h;
        #pragma unroll
        for (int j = 0; j < 8; j++) h[j] = (_Float16)Kl[l31 * 132 + kc * 16 + q5 * 8 + j];
        *(half8v*)(K16s + (((size_t)nt * 8 + kc) * 64 + lane) * 8) = h;
    }
    #pragma unroll
    for (int rep = 0; rep < 2; rep++) {              // 512 V chunks
        int ch = t + rep * 256;
        int dt = ch >> 7, kc2 = (ch >> 6) & 1, lane = ch & 63, l31 = lane & 31, q5 = (lane >> 5) & 1;
        half8v h;
        #pragma unroll
        for (int j = 0; j < 8; j++) h[j] = (_Float16)Vl[(kc2 * 16 + q5 * 8 + j) * 132 + dt * 32 + l31];
        *(half8v*)(Vs + ((((size_t)nt * 4 + dt) * 2 + kc2) * 64 + lane) * 8) = h;
    }
}

// ---------------------------------------------------------------------------
// Main flash kernel. 4 waves x 32 query rows; BN=32 keys/iter. S^T = K.Q^T
// (32x32x16 mfma) so softmax state is per-lane. All K/V fragment loads are
// coalesced 1KB wave loads from the pre-swizzled layouts.
// ---------------------------------------------------------------------------
__launch_bounds__(256, 4)
__global__ void fa_main(const float* __restrict__ Qp, const _Float16* __restrict__ K16s,
                        const _Float16* __restrict__ Vs, float* __restrict__ Opart,
                        float* __restrict__ lpart, float* __restrict__ mpart, int tiles) {
    const int tid  = threadIdx.x;
    const int lane = tid & 63;
    const int wv   = tid >> 6;
    const int l31  = lane & 31;
    const int q5   = lane >> 5;
    const int m0   = blockIdx.x * 128 + wv * 32;
    const int sp   = blockIdx.y;
    const float LOG2E = 1.44269504088896f;

    // Q B-fragments: B[k=d][col=m], col = l31, k = kc*16 + q5*8 + j (log2e folded)
    half8v qf[8];
    {
        const float* qrow = Qp + (size_t)(m0 + l31) * HDIM;
        #pragma unroll
        for (int kc = 0; kc < 8; kc++) {
            const float4 a = *(const float4*)(qrow + kc * 16 + q5 * 8);
            const float4 b = *(const float4*)(qrow + kc * 16 + q5 * 8 + 4);
            half8v h;
            h[0] = (_Float16)(a.x * LOG2E); h[1] = (_Float16)(a.y * LOG2E);
            h[2] = (_Float16)(a.z * LOG2E); h[3] = (_Float16)(a.w * LOG2E);
            h[4] = (_Float16)(b.x * LOG2E); h[5] = (_Float16)(b.y * LOG2E);
            h[6] = (_Float16)(b.z * LOG2E); h[7] = (_Float16)(b.w * LOG2E);
            qf[kc] = h;
        }
    }

    floatx16 oacc[4];
    #pragma unroll
    for (int dt = 0; dt < 4; dt++)
        #pragma unroll
        for (int r = 0; r < 16; r++) oacc[dt][r] = 0.0f;

    float runm = -3.0e38f;
    float lsum = 0.0f;

    const int nt0 = sp * tiles;
    for (int it = 0; it < tiles; ++it) {
        const size_t nt = nt0 + it;
        // ---- V fragments (independent: issue first) + K fragments, coalesced ----
        half8v vf[8];
        #pragma unroll
        for (int dt = 0; dt < 4; dt++)
            #pragma unroll
            for (int kc2 = 0; kc2 < 2; kc2++)
                vf[dt * 2 + kc2] = *(const half8v*)(Vs + (((nt * 4 + dt) * 2 + kc2) * 64 + lane) * 8);
        half8v kf[8];
        #pragma unroll
        for (int kc = 0; kc < 8; kc++)
            kf[kc] = *(const half8v*)(K16s + ((nt * 8 + kc) * 64 + lane) * 8);
        // ---- S^T = K.Q^T, two independent 4-deep chains ----
        floatx16 s0, s1;
        #pragma unroll
        for (int r = 0; r < 16; r++) { s0[r] = 0.0f; s1[r] = 0.0f; }
        #pragma unroll
        for (int kc = 0; kc < 4; kc++)
            s0 = __builtin_amdgcn_mfma_f32_32x32x16_f16(kf[kc], qf[kc], s0, 0, 0, 0);
        #pragma unroll
        for (int kc = 4; kc < 8; kc++)
            s1 = __builtin_amdgcn_mfma_f32_32x32x16_f16(kf[kc], qf[kc], s1, 0, 0, 0);
        float sc[16];
        #pragma unroll
        for (int r = 0; r < 16; r++) sc[r] = s0[r] + s1[r];
        // ---- row max (tree) + cross-half-wave ----
        float tm[8];
        #pragma unroll
        for (int r = 0; r < 8; r++) tm[r] = fmaxf(sc[r], sc[r + 8]);
        #pragma unroll
        for (int w = 4; w; w >>= 1)
            #pragma unroll
            for (int r = 0; r < w; r++) tm[r] = fmaxf(tm[r], tm[r + w]);
        float cmax = fmaxf(tm[0], __shfl_xor(tm[0], 32, 64));
        // ---- lazy rescale: only when max rose by >12 (p stays <= 2^12) ----
        if (__any(cmax > runm + 12.0f)) {
            const float mnew  = fmaxf(runm, cmax);
            const float alpha = __builtin_amdgcn_exp2f(runm - mnew);
            runm = mnew;
            lsum *= alpha;
            #pragma unroll
            for (int dt = 0; dt < 4; dt++)
                #pragma unroll
                for (int r = 0; r < 16; r++) oacc[dt][r] *= alpha;
        }
        // ---- p = exp2(s - runm), tree sum ----
        float p[16];
        #pragma unroll
        for (int r = 0; r < 16; r++) p[r] = __builtin_amdgcn_exp2f(sc[r] - runm);
        float ts[8];
        #pragma unroll
        for (int r = 0; r < 8; r++) ts[r] = p[r] + p[r + 8];
        #pragma unroll
        for (int w = 4; w; w >>= 1)
            #pragma unroll
            for (int r = 0; r < w; r++) ts[r] += ts[r + w];
        lsum += ts[0];
        // ---- P^T (C-layout) -> PV B-operand layout, in registers ----
        uint32 hpk[8];
        #pragma unroll
        for (int t2 = 0; t2 < 8; t2++) {
            auto pk = __builtin_amdgcn_cvt_pkrtz(p[2 * t2], p[2 * t2 + 1]);
            hpk[t2] = __builtin_bit_cast(uint32, pk);
        }
        #pragma unroll
        for (int kc2 = 0; kc2 < 2; kc2++) {
            uint32 pass0 = q5 ? hpk[4 * kc2 + 0] : hpk[4 * kc2 + 2];
            uint32 pass1 = q5 ? hpk[4 * kc2 + 1] : hpk[4 * kc2 + 3];
            uint32 r0 = (uint32)__shfl_xor((int)pass0, 32, 64);
            uint32 r1 = (uint32)__shfl_xor((int)pass1, 32, 64);
            uint32 b0 = q5 ? r0 : hpk[4 * kc2 + 0];
            uint32 b1 = q5 ? r1 : hpk[4 * kc2 + 1];
            uint32 b2 = q5 ? hpk[4 * kc2 + 2] : r0;
            uint32 b3 = q5 ? hpk[4 * kc2 + 3] : r1;
            uint4 bu = make_uint4(b0, b1, b2, b3);
            half8v bfrag = __builtin_bit_cast(half8v, bu);
            #pragma unroll
            for (int dt = 0; dt < 4; dt++)
                oacc[dt] = __builtin_amdgcn_mfma_f32_32x32x16_f16(vf[dt * 2 + kc2], bfrag, oacc[dt], 0, 0, 0);
        }
    }

    // ---- epilogue: per-row (l, m) + unnormalized O^T partial ----
    float ltot = lsum + __shfl_xor(lsum, 32, 64);
    if (lane < 32) {
        lpart[(size_t)sp * N_SEQ + m0 + l31] = ltot;
        mpart[(size_t)sp * N_SEQ + m0 + l31] = runm;
    }
    #pragma unroll
    for (int dt = 0; dt < 4; dt++)
        #pragma unroll
        for (int r = 0; r < 16; r++) {
            int d = dt * 32 + (r & 3) + 8 * (r >> 2) + 4 * q5;
            Opart[((size_t)sp * HDIM + d) * N_SEQ + m0 + l31] = oacc[dt][r];
        }
}

// ---------------------------------------------------------------------------
// Merge: grid (N/64, D/32) = 512 blocks. Combine splits, normalize, LDS
// transpose to row-major coalesced output.
// ---------------------------------------------------------------------------
__global__ void fa_merge(const float* __restrict__ Opart, const float* __restrict__ lpart,
                         const float* __restrict__ mpart, float* __restrict__ Out, int S) {
    __shared__ float lds[64 * 33];
    const int t  = threadIdx.x;
    const int m0 = blockIdx.x * 64;
    const int i  = t & 63;                           // m-local (one wave = one g)
    const int g  = t >> 6;                           // 8-d group
    const int m  = m0 + i;
    const int d0 = blockIdx.y * 32 + g * 8;

    float M = -3.0e38f;
    for (int s = 0; s < S; s++) M = fmaxf(M, mpart[(size_t)s * N_SEQ + m]);
    float L = 0.0f;
    for (int s = 0; s < S; s++)
        L += lpart[(size_t)s * N_SEQ + m] * __builtin_amdgcn_exp2f(mpart[(size_t)s * N_SEQ + m] - M);
    const float inv = 1.0f / L;

    float acc[8];
    #pragma unroll
    for (int dd = 0; dd < 8; dd++) acc[dd] = 0.0f;
    for (int s = 0; s < S; s++) {
        const float ww = __builtin_amdgcn_exp2f(mpart[(size_t)s * N_SEQ + m] - M) * inv;
        #pragma unroll
        for (int dd = 0; dd < 8; dd++)
            acc[dd] += Opart[((size_t)s * HDIM + d0 + dd) * N_SEQ + m] * ww;
    }
    #pragma unroll
    for (int dd = 0; dd < 8; dd++) lds[i * 33 + g * 8 + dd] = acc[dd];
    __syncthreads();
    const int mi = t >> 2, c = t & 3;                // 16 m x 4 c per wave
    float4 v0, v1;
    const float* row = &lds[mi * 33 + c * 8];
    v0.x = row[0]; v0.y = row[1]; v0.z = row[2]; v0.w = row[3];
    v1.x = row[4]; v1.y = row[5]; v1.z = row[6]; v1.w = row[7];
    float* outp = Out + (size_t)(m0 + mi) * HDIM + blockIdx.y * 32 + c * 8;
    *(float4*)(outp)     = v0;
    *(float4*)(outp + 4) = v1;
}

// ---------------------------------------------------------------------------
// Safety-net: naive fp32 flash attention (only if ws too small).
// ---------------------------------------------------------------------------
__global__ void fa_naive(const float* __restrict__ Q, const float* __restrict__ K,
                         const float* __restrict__ V, float* __restrict__ O) {
    const int m = blockIdx.x;
    const int t = threadIdx.x;
    __shared__ float qs[HDIM];
    __shared__ float ps[256];
    __shared__ float red[256];
    if (t < HDIM) qs[t] = Q[(size_t)m * HDIM + t] * 1.44269504f;
    __syncthreads();
    float om = -3.0e38f, ls = 0.0f, oa = 0.0f;
    for (int nb = 0; nb < N_SEQ; nb += 256) {
        const float* kr = K + (size_t)(nb + t) * HDIM;
        float s = 0.0f;
        #pragma unroll 8
        for (int d = 0; d < HDIM; d++) s += qs[d] * kr[d];
        red[t] = s; __syncthreads();
        for (int st = 128; st > 0; st >>= 1) { if (t < st) red[t] = fmaxf(red[t], red[t + st]); __syncthreads(); }
        float cm = red[0];
        __syncthreads();
        float mn = fmaxf(om, cm);
        float al = __builtin_amdgcn_exp2f(om - mn);
        om = mn;
        float pp = __builtin_amdgcn_exp2f(s - mn);
        ps[t] = pp; red[t] = pp; __syncthreads();
        for (int st = 128; st > 0; st >>= 1) { if (t < st) red[t] += red[t + st]; __syncthreads(); }
        float csum = red[0];
        ls = ls * al + csum;
        if (t < HDIM) {
            float acc = 0.0f;
            for (int j = 0; j < 256; j++) acc += ps[j] * V[(size_t)(nb + j) * HDIM + t];
            oa = oa * al + acc;
        }
        __syncthreads();
    }
    if (t < HDIM) O[(size_t)m * HDIM + t] = oa / ls;
}

// ---------------------------------------------------------------------------
extern "C" void kernel_launch(void* const* d_in, const int* in_sizes, int n_in,
                              void* d_out, int out_size, void* d_ws, size_t ws_size,
                              hipStream_t stream) {
    const float* q = (const float*)d_in[0];
    const float* k = (const float*)d_in[1];
    const float* v = (const float*)d_in[2];
    float* out = (float*)d_out;

    const size_t MB = 1024ull * 1024ull;
    int S = 0;
    for (int s = 16; s >= 1; s >>= 1) {
        size_t need = 4 * MB + (size_t)s * (4 * MB + 64 * 1024);
        if (ws_size >= need) { S = s; break; }
    }
    if (S == 0) {
        fa_naive<<<N_SEQ, 256, 0, stream>>>(q, k, v, out);
        return;
    }
    char* ws = (char*)d_ws;
    _Float16* K16s = (_Float16*)ws;
    _Float16* Vs   = (_Float16*)(ws + 2 * MB);
    float* Opart   = (float*)(ws + 4 * MB);
    float* lpart   = (float*)(ws + 4 * MB + (size_t)S * 4 * MB);
    float* mpart   = lpart + (size_t)S * N_SEQ;

    prep_kv<<<dim3(N_SEQ / 32), dim3(256), 0, stream>>>(k, v, K16s, Vs);
    fa_main<<<dim3(N_SEQ / 128, S), dim3(256), 0, stream>>>(q, K16s, Vs, Opart, lpart, mpart, (N_SEQ / 32) / S);
    fa_merge<<<dim3(N_SEQ / 64, HDIM / 32), dim3(256), 0, stream>>>(Opart, lpart, mpart, out, S);
}

// Round 5
// 128.821 us; speedup vs baseline: 1.9868x; 1.9868x over previous
//
#include <hip/hip_runtime.h>

#define N_SEQ 8192
#define HDIM  128

typedef _Float16 half8v  __attribute__((ext_vector_type(8)));
typedef float    floatx16 __attribute__((ext_vector_type(16)));
typedef unsigned int uint32;

// ---------------------------------------------------------------------------
// prep_kv: one block per 32-key tile. Stages K and V fp32 tiles in LDS, then
// writes f16 fragments in EXACT mfma operand order, lane-major, so fa_main's
// fragment loads are fully coalesced 1KB wave loads.
//   K16s[((nt*8 + kc)*64 + lane)*8 + j]  = K[nt*32 + l31][kc*16 + q5*8 + j]
//   Vs[(((nt*4+dt)*2+kc2)*64 + lane)*8+j]= V[nt*32 + kc2*16+q5*8+j][dt*32+l31]
// ---------------------------------------------------------------------------
__global__ void prep_kv(const float* __restrict__ K, const float* __restrict__ V,
                        _Float16* __restrict__ K16s, _Float16* __restrict__ Vs) {
    __shared__ float Kl[32 * 132];
    __shared__ float Vl[32 * 132];
    const int t  = threadIdx.x;
    const int nt = blockIdx.x;
    const int n0 = nt * 32;
    #pragma unroll
    for (int kk = 0; kk < 4; kk++) {
        int idx = t + 256 * kk;                      // 1024 float4s = 32x128
        int nl = idx >> 5, c4 = idx & 31;
        float4 f = *(((const float4*)(K + (size_t)(n0 + nl) * HDIM)) + c4);
        float* dk = &Kl[nl * 132 + c4 * 4];
        dk[0] = f.x; dk[1] = f.y; dk[2] = f.z; dk[3] = f.w;
        float4 g = *(((const float4*)(V + (size_t)(n0 + nl) * HDIM)) + c4);
        float* dv = &Vl[nl * 132 + c4 * 4];
        dv[0] = g.x; dv[1] = g.y; dv[2] = g.z; dv[3] = g.w;
    }
    __syncthreads();
    #pragma unroll
    for (int rep = 0; rep < 2; rep++) {              // 512 K chunks
        int ch = t + rep * 256;
        int kc = ch >> 6, lane = ch & 63, l31 = lane & 31, q5 = (lane >> 5) & 1;
        half8v h;
        #pragma unroll
        for (int j = 0; j < 8; j++) h[j] = (_Float16)Kl[l31 * 132 + kc * 16 + q5 * 8 + j];
        *(half8v*)(K16s + (((size_t)nt * 8 + kc) * 64 + lane) * 8) = h;
    }
    #pragma unroll
    for (int rep = 0; rep < 2; rep++) {              // 512 V chunks
        int ch = t + rep * 256;
        int dt = ch >> 7, kc2 = (ch >> 6) & 1, lane = ch & 63, l31 = lane & 31, q5 = (lane >> 5) & 1;
        half8v h;
        #pragma unroll
        for (int j = 0; j < 8; j++) h[j] = (_Float16)Vl[(kc2 * 16 + q5 * 8 + j) * 132 + dt * 32 + l31];
        *(half8v*)(Vs + ((((size_t)nt * 4 + dt) * 2 + kc2) * 64 + lane) * 8) = h;
    }
}

// ---------------------------------------------------------------------------
// Main flash kernel. 4 waves x 32 query rows; BN=32 keys/iter. S^T = K.Q^T
// (32x32x16 mfma) so softmax state is per-lane. All K/V fragment loads are
// coalesced 1KB wave loads from the pre-swizzled layouts. Partials leave via
// nontemporal stores so the write stream doesn't evict K/V from L2.
// ---------------------------------------------------------------------------
__launch_bounds__(256, 2)
__global__ void fa_main(const float* __restrict__ Qp, const _Float16* __restrict__ K16s,
                        const _Float16* __restrict__ Vs, float* __restrict__ Opart,
                        float* __restrict__ lpart, float* __restrict__ mpart, int tiles) {
    const int tid  = threadIdx.x;
    const int lane = tid & 63;
    const int wv   = tid >> 6;
    const int l31  = lane & 31;
    const int q5   = lane >> 5;
    const int m0   = blockIdx.x * 128 + wv * 32;
    const int sp   = blockIdx.y;
    const float LOG2E = 1.44269504088896f;

    // Q B-fragments: B[k=d][col=m], col = l31, k = kc*16 + q5*8 + j (log2e folded)
    half8v qf[8];
    {
        const float* qrow = Qp + (size_t)(m0 + l31) * HDIM;
        #pragma unroll
        for (int kc = 0; kc < 8; kc++) {
            const float4 a = *(const float4*)(qrow + kc * 16 + q5 * 8);
            const float4 b = *(const float4*)(qrow + kc * 16 + q5 * 8 + 4);
            half8v h;
            h[0] = (_Float16)(a.x * LOG2E); h[1] = (_Float16)(a.y * LOG2E);
            h[2] = (_Float16)(a.z * LOG2E); h[3] = (_Float16)(a.w * LOG2E);
            h[4] = (_Float16)(b.x * LOG2E); h[5] = (_Float16)(b.y * LOG2E);
            h[6] = (_Float16)(b.z * LOG2E); h[7] = (_Float16)(b.w * LOG2E);
            qf[kc] = h;
        }
    }

    floatx16 oacc[4];
    #pragma unroll
    for (int dt = 0; dt < 4; dt++)
        #pragma unroll
        for (int r = 0; r < 16; r++) oacc[dt][r] = 0.0f;

    float runm = -3.0e38f;
    float lsum = 0.0f;

    const int nt0 = sp * tiles;
    for (int it = 0; it < tiles; ++it) {
        const size_t nt = nt0 + it;
        // ---- V fragments (independent: issue first) + K fragments, coalesced ----
        half8v vf[8];
        #pragma unroll
        for (int dt = 0; dt < 4; dt++)
            #pragma unroll
            for (int kc2 = 0; kc2 < 2; kc2++)
                vf[dt * 2 + kc2] = *(const half8v*)(Vs + (((nt * 4 + dt) * 2 + kc2) * 64 + lane) * 8);
        half8v kf[8];
        #pragma unroll
        for (int kc = 0; kc < 8; kc++)
            kf[kc] = *(const half8v*)(K16s + ((nt * 8 + kc) * 64 + lane) * 8);
        // ---- S^T = K.Q^T, two independent 4-deep chains ----
        floatx16 s0, s1;
        #pragma unroll
        for (int r = 0; r < 16; r++) { s0[r] = 0.0f; s1[r] = 0.0f; }
        #pragma unroll
        for (int kc = 0; kc < 4; kc++)
            s0 = __builtin_amdgcn_mfma_f32_32x32x16_f16(kf[kc], qf[kc], s0, 0, 0, 0);
        #pragma unroll
        for (int kc = 4; kc < 8; kc++)
            s1 = __builtin_amdgcn_mfma_f32_32x32x16_f16(kf[kc], qf[kc], s1, 0, 0, 0);
        float sc[16];
        #pragma unroll
        for (int r = 0; r < 16; r++) sc[r] = s0[r] + s1[r];
        // ---- row max (tree) + cross-half-wave ----
        float tm[8];
        #pragma unroll
        for (int r = 0; r < 8; r++) tm[r] = fmaxf(sc[r], sc[r + 8]);
        #pragma unroll
        for (int w = 4; w; w >>= 1)
            #pragma unroll
            for (int r = 0; r < w; r++) tm[r] = fmaxf(tm[r], tm[r + w]);
        float cmax = fmaxf(tm[0], __shfl_xor(tm[0], 32, 64));
        // ---- lazy rescale: only when max rose by >12 (p stays <= 2^12) ----
        if (__any(cmax > runm + 12.0f)) {
            const float mnew  = fmaxf(runm, cmax);
            const float alpha = __builtin_amdgcn_exp2f(runm - mnew);
            runm = mnew;
            lsum *= alpha;
            #pragma unroll
            for (int dt = 0; dt < 4; dt++)
                #pragma unroll
                for (int r = 0; r < 16; r++) oacc[dt][r] *= alpha;
        }
        // ---- p = exp2(s - runm), tree sum ----
        float p[16];
        #pragma unroll
        for (int r = 0; r < 16; r++) p[r] = __builtin_amdgcn_exp2f(sc[r] - runm);
        float ts[8];
        #pragma unroll
        for (int r = 0; r < 8; r++) ts[r] = p[r] + p[r + 8];
        #pragma unroll
        for (int w = 4; w; w >>= 1)
            #pragma unroll
            for (int r = 0; r < w; r++) ts[r] += ts[r + w];
        lsum += ts[0];
        // ---- P^T (C-layout) -> PV B-operand layout, in registers ----
        uint32 hpk[8];
        #pragma unroll
        for (int t2 = 0; t2 < 8; t2++) {
            auto pk = __builtin_amdgcn_cvt_pkrtz(p[2 * t2], p[2 * t2 + 1]);
            hpk[t2] = __builtin_bit_cast(uint32, pk);
        }
        #pragma unroll
        for (int kc2 = 0; kc2 < 2; kc2++) {
            uint32 pass0 = q5 ? hpk[4 * kc2 + 0] : hpk[4 * kc2 + 2];
            uint32 pass1 = q5 ? hpk[4 * kc2 + 1] : hpk[4 * kc2 + 3];
            uint32 r0 = (uint32)__shfl_xor((int)pass0, 32, 64);
            uint32 r1 = (uint32)__shfl_xor((int)pass1, 32, 64);
            uint32 b0 = q5 ? r0 : hpk[4 * kc2 + 0];
            uint32 b1 = q5 ? r1 : hpk[4 * kc2 + 1];
            uint32 b2 = q5 ? hpk[4 * kc2 + 2] : r0;
            uint32 b3 = q5 ? hpk[4 * kc2 + 3] : r1;
            uint4 bu = make_uint4(b0, b1, b2, b3);
            half8v bfrag = __builtin_bit_cast(half8v, bu);
            #pragma unroll
            for (int dt = 0; dt < 4; dt++)
                oacc[dt] = __builtin_amdgcn_mfma_f32_32x32x16_f16(vf[dt * 2 + kc2], bfrag, oacc[dt], 0, 0, 0);
        }
    }

    // ---- epilogue: per-row (l, m) + unnormalized O^T partial (nontemporal) ----
    float ltot = lsum + __shfl_xor(lsum, 32, 64);
    if (lane < 32) {
        __builtin_nontemporal_store(ltot, &lpart[(size_t)sp * N_SEQ + m0 + l31]);
        __builtin_nontemporal_store(runm, &mpart[(size_t)sp * N_SEQ + m0 + l31]);
    }
    #pragma unroll
    for (int dt = 0; dt < 4; dt++)
        #pragma unroll
        for (int r = 0; r < 16; r++) {
            int d = dt * 32 + (r & 3) + 8 * (r >> 2) + 4 * q5;
            __builtin_nontemporal_store(oacc[dt][r],
                &Opart[((size_t)sp * HDIM + d) * N_SEQ + m0 + l31]);
        }
}

// ---------------------------------------------------------------------------
// Merge: grid (N/64, D/32) = 512 blocks. Combine splits, normalize, LDS
// transpose to row-major coalesced output. Nontemporal Opart reads (no reuse).
// ---------------------------------------------------------------------------
__global__ void fa_merge(const float* __restrict__ Opart, const float* __restrict__ lpart,
                         const float* __restrict__ mpart, float* __restrict__ Out, int S) {
    __shared__ float lds[64 * 33];
    const int t  = threadIdx.x;
    const int m0 = blockIdx.x * 64;
    const int i  = t & 63;                           // m-local (one wave = one g)
    const int g  = t >> 6;                           // 8-d group
    const int m  = m0 + i;
    const int d0 = blockIdx.y * 32 + g * 8;

    float M = -3.0e38f;
    for (int s = 0; s < S; s++) M = fmaxf(M, mpart[(size_t)s * N_SEQ + m]);
    float L = 0.0f;
    for (int s = 0; s < S; s++)
        L += lpart[(size_t)s * N_SEQ + m] * __builtin_amdgcn_exp2f(mpart[(size_t)s * N_SEQ + m] - M);
    const float inv = 1.0f / L;

    float acc[8];
    #pragma unroll
    for (int dd = 0; dd < 8; dd++) acc[dd] = 0.0f;
    for (int s = 0; s < S; s++) {
        const float ww = __builtin_amdgcn_exp2f(mpart[(size_t)s * N_SEQ + m] - M) * inv;
        #pragma unroll
        for (int dd = 0; dd < 8; dd++)
            acc[dd] += __builtin_nontemporal_load(
                &Opart[((size_t)s * HDIM + d0 + dd) * N_SEQ + m]) * ww;
    }
    #pragma unroll
    for (int dd = 0; dd < 8; dd++) lds[i * 33 + g * 8 + dd] = acc[dd];
    __syncthreads();
    const int mi = t >> 2, c = t & 3;                // 16 m x 4 c per wave
    float4 v0, v1;
    const float* row = &lds[mi * 33 + c * 8];
    v0.x = row[0]; v0.y = row[1]; v0.z = row[2]; v0.w = row[3];
    v1.x = row[4]; v1.y = row[5]; v1.z = row[6]; v1.w = row[7];
    float* outp = Out + (size_t)(m0 + mi) * HDIM + blockIdx.y * 32 + c * 8;
    *(float4*)(outp)     = v0;
    *(float4*)(outp + 4) = v1;
}

// ---------------------------------------------------------------------------
// Safety-net: naive fp32 flash attention (only if ws too small).
// ---------------------------------------------------------------------------
__global__ void fa_naive(const float* __restrict__ Q, const float* __restrict__ K,
                         const float* __restrict__ V, float* __restrict__ O) {
    const int m = blockIdx.x;
    const int t = threadIdx.x;
    __shared__ float qs[HDIM];
    __shared__ float ps[256];
    __shared__ float red[256];
    if (t < HDIM) qs[t] = Q[(size_t)m * HDIM + t] * 1.44269504f;
    __syncthreads();
    float om = -3.0e38f, ls = 0.0f, oa = 0.0f;
    for (int nb = 0; nb < N_SEQ; nb += 256) {
        const float* kr = K + (size_t)(nb + t) * HDIM;
        float s = 0.0f;
        #pragma unroll 8
        for (int d = 0; d < HDIM; d++) s += qs[d] * kr[d];
        red[t] = s; __syncthreads();
        for (int st = 128; st > 0; st >>= 1) { if (t < st) red[t] = fmaxf(red[t], red[t + st]); __syncthreads(); }
        float cm = red[0];
        __syncthreads();
        float mn = fmaxf(om, cm);
        float al = __builtin_amdgcn_exp2f(om - mn);
        om = mn;
        float pp = __builtin_amdgcn_exp2f(s - mn);
        ps[t] = pp; red[t] = pp; __syncthreads();
        for (int st = 128; st > 0; st >>= 1) { if (t < st) red[t] += red[t + st]; __syncthreads(); }
        float csum = red[0];
        ls = ls * al + csum;
        if (t < HDIM) {
            float acc = 0.0f;
            for (int j = 0; j < 256; j++) acc += ps[j] * V[(size_t)(nb + j) * HDIM + t];
            oa = oa * al + acc;
        }
        __syncthreads();
    }
    if (t < HDIM) O[(size_t)m * HDIM + t] = oa / ls;
}

// ---------------------------------------------------------------------------
extern "C" void kernel_launch(void* const* d_in, const int* in_sizes, int n_in,
                              void* d_out, int out_size, void* d_ws, size_t ws_size,
                              hipStream_t stream) {
    const float* q = (const float*)d_in[0];
    const float* k = (const float*)d_in[1];
    const float* v = (const float*)d_in[2];
    float* out = (float*)d_out;

    const size_t MB = 1024ull * 1024ull;
    int S = 0;
    for (int s = 8; s >= 1; s >>= 1) {               // S=8: cache-healthy config (r2/r3)
        size_t need = 4 * MB + (size_t)s * (4 * MB + 64 * 1024);
        if (ws_size >= need) { S = s; break; }
    }
    if (S == 0) {
        fa_naive<<<N_SEQ, 256, 0, stream>>>(q, k, v, out);
        return;
    }
    char* ws = (char*)d_ws;
    _Float16* K16s = (_Float16*)ws;
    _Float16* Vs   = (_Float16*)(ws + 2 * MB);
    float* Opart   = (float*)(ws + 4 * MB);
    float* lpart   = (float*)(ws + 4 * MB + (size_t)S * 4 * MB);
    float* mpart   = lpart + (size_t)S * N_SEQ;

    prep_kv<<<dim3(N_SEQ / 32), dim3(256), 0, stream>>>(k, v, K16s, Vs);
    fa_main<<<dim3(N_SEQ / 128, S), dim3(256), 0, stream>>>(q, K16s, Vs, Opart, lpart, mpart, (N_SEQ / 32) / S);
    fa_merge<<<dim3(N_SEQ / 64, HDIM / 32), dim3(256), 0, stream>>>(Opart, lpart, mpart, out, S);
}

// Round 6
// 126.740 us; speedup vs baseline: 2.0194x; 1.0164x over previous
//
#include <hip/hip_runtime.h>

#define N_SEQ 8192
#define HDIM  128

typedef _Float16 half8v  __attribute__((ext_vector_type(8)));
typedef float    floatx16 __attribute__((ext_vector_type(16)));
typedef unsigned int uint32;

// ---------------------------------------------------------------------------
// prep_kv: one block per 32-key tile. Stages K and V fp32 tiles in LDS, then
// writes f16 fragments in EXACT mfma operand order, lane-major, so fa_main's
// fragment loads are fully coalesced 1KB wave loads.
// ---------------------------------------------------------------------------
__global__ void prep_kv(const float* __restrict__ K, const float* __restrict__ V,
                        _Float16* __restrict__ K16s, _Float16* __restrict__ Vs) {
    __shared__ float Kl[32 * 132];
    __shared__ float Vl[32 * 132];
    const int t  = threadIdx.x;
    const int nt = blockIdx.x;
    const int n0 = nt * 32;
    #pragma unroll
    for (int kk = 0; kk < 4; kk++) {
        int idx = t + 256 * kk;
        int nl = idx >> 5, c4 = idx & 31;
        float4 f = *(((const float4*)(K + (size_t)(n0 + nl) * HDIM)) + c4);
        float* dk = &Kl[nl * 132 + c4 * 4];
        dk[0] = f.x; dk[1] = f.y; dk[2] = f.z; dk[3] = f.w;
        float4 g = *(((const float4*)(V + (size_t)(n0 + nl) * HDIM)) + c4);
        float* dv = &Vl[nl * 132 + c4 * 4];
        dv[0] = g.x; dv[1] = g.y; dv[2] = g.z; dv[3] = g.w;
    }
    __syncthreads();
    #pragma unroll
    for (int rep = 0; rep < 2; rep++) {
        int ch = t + rep * 256;
        int kc = ch >> 6, lane = ch & 63, l31 = lane & 31, q5 = (lane >> 5) & 1;
        half8v h;
        #pragma unroll
        for (int j = 0; j < 8; j++) h[j] = (_Float16)Kl[l31 * 132 + kc * 16 + q5 * 8 + j];
        *(half8v*)(K16s + (((size_t)nt * 8 + kc) * 64 + lane) * 8) = h;
    }
    #pragma unroll
    for (int rep = 0; rep < 2; rep++) {
        int ch = t + rep * 256;
        int dt = ch >> 7, kc2 = (ch >> 6) & 1, lane = ch & 63, l31 = lane & 31, q5 = (lane >> 5) & 1;
        half8v h;
        #pragma unroll
        for (int j = 0; j < 8; j++) h[j] = (_Float16)Vl[(kc2 * 16 + q5 * 8 + j) * 132 + dt * 32 + l31];
        *(half8v*)(Vs + ((((size_t)nt * 4 + dt) * 2 + kc2) * 64 + lane) * 8) = h;
    }
}

// ---- PV: oacc += V(tile) . P(tile), P given as packed-f16 C-layout regs ----
static __device__ __forceinline__ void do_pv(const half8v (&vsrc)[8], const uint32 (&hpk)[8],
                                             floatx16 (&oacc)[4], int q5) {
    #pragma unroll
    for (int kc2 = 0; kc2 < 2; kc2++) {
        uint32 pass0 = q5 ? hpk[4 * kc2 + 0] : hpk[4 * kc2 + 2];
        uint32 pass1 = q5 ? hpk[4 * kc2 + 1] : hpk[4 * kc2 + 3];
        uint32 r0 = (uint32)__shfl_xor((int)pass0, 32, 64);
        uint32 r1 = (uint32)__shfl_xor((int)pass1, 32, 64);
        uint32 b0 = q5 ? r0 : hpk[4 * kc2 + 0];
        uint32 b1 = q5 ? r1 : hpk[4 * kc2 + 1];
        uint32 b2 = q5 ? hpk[4 * kc2 + 2] : r0;
        uint32 b3 = q5 ? hpk[4 * kc2 + 3] : r1;
        uint4 bu = make_uint4(b0, b1, b2, b3);
        half8v bfrag = __builtin_bit_cast(half8v, bu);
        #pragma unroll
        for (int dt = 0; dt < 4; dt++)
            oacc[dt] = __builtin_amdgcn_mfma_f32_32x32x16_f16(vsrc[dt * 2 + kc2], bfrag, oacc[dt], 0, 0, 0);
    }
}

// ---- one pipeline step: loads(t), rescale-if, PV(t-1), S(t), softmax(t) ----
template <bool DO_PV>
static __device__ __forceinline__ void pipe_step(
        const half8v (&qf)[8], half8v (&vin)[8], const half8v (&vprev)[8],
        floatx16 (&oacc)[4], uint32 (&hpk)[8],
        float& runm, float& lsum, float& palpha, bool& pflag,
        const _Float16* __restrict__ K16s, const _Float16* __restrict__ Vs,
        size_t nt, int lane, int q5) {
    // ---- loads for tile t (K used this step after PV burst; V used next step) ----
    half8v kf[8];
    #pragma unroll
    for (int kc = 0; kc < 8; kc++)
        kf[kc] = *(const half8v*)(K16s + ((nt * 8 + kc) * 64 + lane) * 8);
    #pragma unroll
    for (int dt = 0; dt < 4; dt++)
        #pragma unroll
        for (int kc2 = 0; kc2 < 2; kc2++)
            vin[dt * 2 + kc2] = *(const half8v*)(Vs + (((nt * 4 + dt) * 2 + kc2) * 64 + lane) * 8);
    // ---- deferred oacc rescale (alpha from previous softmax) ----
    if (pflag) {
        #pragma unroll
        for (int dt = 0; dt < 4; dt++)
            #pragma unroll
            for (int r = 0; r < 16; r++) oacc[dt][r] *= palpha;
        pflag = false;
    }
    // ---- PV for tile t-1 (independent of this tile's softmax) ----
    if (DO_PV) do_pv(vprev, hpk, oacc, q5);
    // ---- S^T = K.Q^T, two independent 4-deep chains ----
    floatx16 s0, s1;
    #pragma unroll
    for (int r = 0; r < 16; r++) { s0[r] = 0.0f; s1[r] = 0.0f; }
    #pragma unroll
    for (int kc = 0; kc < 4; kc++)
        s0 = __builtin_amdgcn_mfma_f32_32x32x16_f16(kf[kc], qf[kc], s0, 0, 0, 0);
    #pragma unroll
    for (int kc = 4; kc < 8; kc++)
        s1 = __builtin_amdgcn_mfma_f32_32x32x16_f16(kf[kc], qf[kc], s1, 0, 0, 0);
    float sc[16];
    #pragma unroll
    for (int r = 0; r < 16; r++) sc[r] = s0[r] + s1[r];
    // ---- softmax: row max tree + cross-half shfl ----
    float tm[8];
    #pragma unroll
    for (int r = 0; r < 8; r++) tm[r] = fmaxf(sc[r], sc[r + 8]);
    #pragma unroll
    for (int w = 4; w; w >>= 1)
        #pragma unroll
        for (int r = 0; r < w; r++) tm[r] = fmaxf(tm[r], tm[r + w]);
    float cmax = fmaxf(tm[0], __shfl_xor(tm[0], 32, 64));
    // lazy rescale: flag for NEXT step's pre-PV rescale (p stays <= 2^12 in f16)
    if (__any(cmax > runm + 12.0f)) {
        const float mnew = fmaxf(runm, cmax);
        palpha = __builtin_amdgcn_exp2f(runm - mnew);
        runm = mnew;
        lsum *= palpha;
        pflag = true;
    }
    float p[16];
    #pragma unroll
    for (int r = 0; r < 16; r++) p[r] = __builtin_amdgcn_exp2f(sc[r] - runm);
    float ts[8];
    #pragma unroll
    for (int r = 0; r < 8; r++) ts[r] = p[r] + p[r + 8];
    #pragma unroll
    for (int w = 4; w; w >>= 1)
        #pragma unroll
        for (int r = 0; r < w; r++) ts[r] += ts[r + w];
    lsum += ts[0];
    #pragma unroll
    for (int t2 = 0; t2 < 8; t2++) {
        auto pk = __builtin_amdgcn_cvt_pkrtz(p[2 * t2], p[2 * t2 + 1]);
        hpk[t2] = __builtin_bit_cast(uint32, pk);
    }
}

// ---------------------------------------------------------------------------
// Main flash kernel: deferred-PV software pipeline. 4 waves x 32 query rows,
// BN=32 keys/step. All K/V fragment loads coalesced from pre-swizzled layouts.
// ---------------------------------------------------------------------------
__launch_bounds__(256, 2)
__global__ void fa_main(const float* __restrict__ Qp, const _Float16* __restrict__ K16s,
                        const _Float16* __restrict__ Vs, float* __restrict__ Opart,
                        float* __restrict__ lpart, float* __restrict__ mpart, int tiles) {
    const int tid  = threadIdx.x;
    const int lane = tid & 63;
    const int wv   = tid >> 6;
    const int l31  = lane & 31;
    const int q5   = lane >> 5;
    const int m0   = blockIdx.x * 128 + wv * 32;
    const int sp   = blockIdx.y;
    const float LOG2E = 1.44269504088896f;

    half8v qf[8];
    {
        const float* qrow = Qp + (size_t)(m0 + l31) * HDIM;
        #pragma unroll
        for (int kc = 0; kc < 8; kc++) {
            const float4 a = *(const float4*)(qrow + kc * 16 + q5 * 8);
            const float4 b = *(const float4*)(qrow + kc * 16 + q5 * 8 + 4);
            half8v h;
            h[0] = (_Float16)(a.x * LOG2E); h[1] = (_Float16)(a.y * LOG2E);
            h[2] = (_Float16)(a.z * LOG2E); h[3] = (_Float16)(a.w * LOG2E);
            h[4] = (_Float16)(b.x * LOG2E); h[5] = (_Float16)(b.y * LOG2E);
            h[6] = (_Float16)(b.z * LOG2E); h[7] = (_Float16)(b.w * LOG2E);
            qf[kc] = h;
        }
    }

    floatx16 oacc[4];
    #pragma unroll
    for (int dt = 0; dt < 4; dt++)
        #pragma unroll
        for (int r = 0; r < 16; r++) oacc[dt][r] = 0.0f;

    float runm = -3.0e38f;
    float lsum = 0.0f;
    float palpha = 0.0f;
    bool  pflag = false;
    uint32 hpk[8];
    half8v va[8], vb[8];

    const size_t nt0 = (size_t)sp * tiles;
    // preamble: tile 0 S+softmax (no PV yet)
    pipe_step<false>(qf, va, va, oacc, hpk, runm, lsum, palpha, pflag, K16s, Vs, nt0, lane, q5);
    // steady state: pairs keep buffers in fixed registers (no indexed arrays)
    for (int p = 0; p < (tiles - 2) / 2; p++) {
        pipe_step<true>(qf, vb, va, oacc, hpk, runm, lsum, palpha, pflag, K16s, Vs, nt0 + 1 + 2 * p, lane, q5);
        pipe_step<true>(qf, va, vb, oacc, hpk, runm, lsum, palpha, pflag, K16s, Vs, nt0 + 2 + 2 * p, lane, q5);
    }
    pipe_step<true>(qf, vb, va, oacc, hpk, runm, lsum, palpha, pflag, K16s, Vs, nt0 + tiles - 1, lane, q5);
    // finale: rescale-if + last tile's PV
    if (pflag) {
        #pragma unroll
        for (int dt = 0; dt < 4; dt++)
            #pragma unroll
            for (int r = 0; r < 16; r++) oacc[dt][r] *= palpha;
    }
    do_pv(vb, hpk, oacc, q5);

    // ---- epilogue: per-row (l, m) + unnormalized O^T partial (nontemporal) ----
    float ltot = lsum + __shfl_xor(lsum, 32, 64);
    if (lane < 32) {
        __builtin_nontemporal_store(ltot, &lpart[(size_t)sp * N_SEQ + m0 + l31]);
        __builtin_nontemporal_store(runm, &mpart[(size_t)sp * N_SEQ + m0 + l31]);
    }
    #pragma unroll
    for (int dt = 0; dt < 4; dt++)
        #pragma unroll
        for (int r = 0; r < 16; r++) {
            int d = dt * 32 + (r & 3) + 8 * (r >> 2) + 4 * q5;
            __builtin_nontemporal_store(oacc[dt][r],
                &Opart[((size_t)sp * HDIM + d) * N_SEQ + m0 + l31]);
        }
}

// ---------------------------------------------------------------------------
// Merge: grid (N/64, D/32) = 512 blocks. Combine splits, normalize, LDS
// transpose to row-major coalesced output. Nontemporal Opart reads (no reuse).
// ---------------------------------------------------------------------------
__global__ void fa_merge(const float* __restrict__ Opart, const float* __restrict__ lpart,
                         const float* __restrict__ mpart, float* __restrict__ Out, int S) {
    __shared__ float lds[64 * 33];
    const int t  = threadIdx.x;
    const int m0 = blockIdx.x * 64;
    const int i  = t & 63;
    const int g  = t >> 6;
    const int m  = m0 + i;
    const int d0 = blockIdx.y * 32 + g * 8;

    float M = -3.0e38f;
    for (int s = 0; s < S; s++) M = fmaxf(M, mpart[(size_t)s * N_SEQ + m]);
    float L = 0.0f;
    for (int s = 0; s < S; s++)
        L += lpart[(size_t)s * N_SEQ + m] * __builtin_amdgcn_exp2f(mpart[(size_t)s * N_SEQ + m] - M);
    const float inv = 1.0f / L;

    float acc[8];
    #pragma unroll
    for (int dd = 0; dd < 8; dd++) acc[dd] = 0.0f;
    for (int s = 0; s < S; s++) {
        const float ww = __builtin_amdgcn_exp2f(mpart[(size_t)s * N_SEQ + m] - M) * inv;
        #pragma unroll
        for (int dd = 0; dd < 8; dd++)
            acc[dd] += __builtin_nontemporal_load(
                &Opart[((size_t)s * HDIM + d0 + dd) * N_SEQ + m]) * ww;
    }
    #pragma unroll
    for (int dd = 0; dd < 8; dd++) lds[i * 33 + g * 8 + dd] = acc[dd];
    __syncthreads();
    const int mi = t >> 2, c = t & 3;
    float4 v0, v1;
    const float* row = &lds[mi * 33 + c * 8];
    v0.x = row[0]; v0.y = row[1]; v0.z = row[2]; v0.w = row[3];
    v1.x = row[4]; v1.y = row[5]; v1.z = row[6]; v1.w = row[7];
    float* outp = Out + (size_t)(m0 + mi) * HDIM + blockIdx.y * 32 + c * 8;
    *(float4*)(outp)     = v0;
    *(float4*)(outp + 4) = v1;
}

// ---------------------------------------------------------------------------
// Safety-net: naive fp32 flash attention (only if ws too small).
// ---------------------------------------------------------------------------
__global__ void fa_naive(const float* __restrict__ Q, const float* __restrict__ K,
                         const float* __restrict__ V, float* __restrict__ O) {
    const int m = blockIdx.x;
    const int t = threadIdx.x;
    __shared__ float qs[HDIM];
    __shared__ float ps[256];
    __shared__ float red[256];
    if (t < HDIM) qs[t] = Q[(size_t)m * HDIM + t] * 1.44269504f;
    __syncthreads();
    float om = -3.0e38f, ls = 0.0f, oa = 0.0f;
    for (int nb = 0; nb < N_SEQ; nb += 256) {
        const float* kr = K + (size_t)(nb + t) * HDIM;
        float s = 0.0f;
        #pragma unroll 8
        for (int d = 0; d < HDIM; d++) s += qs[d] * kr[d];
        red[t] = s; __syncthreads();
        for (int st = 128; st > 0; st >>= 1) { if (t < st) red[t] = fmaxf(red[t], red[t + st]); __syncthreads(); }
        float cm = red[0];
        __syncthreads();
        float mn = fmaxf(om, cm);
        float al = __builtin_amdgcn_exp2f(om - mn);
        om = mn;
        float pp = __builtin_amdgcn_exp2f(s - mn);
        ps[t] = pp; red[t] = pp; __syncthreads();
        for (int st = 128; st > 0; st >>= 1) { if (t < st) red[t] += red[t + st]; __syncthreads(); }
        float csum = red[0];
        ls = ls * al + csum;
        if (t < HDIM) {
            float acc = 0.0f;
            for (int j = 0; j < 256; j++) acc += ps[j] * V[(size_t)(nb + j) * HDIM + t];
            oa = oa * al + acc;
        }
        __syncthreads();
    }
    if (t < HDIM) O[(size_t)m * HDIM + t] = oa / ls;
}

// ---------------------------------------------------------------------------
extern "C" void kernel_launch(void* const* d_in, const int* in_sizes, int n_in,
                              void* d_out, int out_size, void* d_ws, size_t ws_size,
                              hipStream_t stream) {
    const float* q = (const float*)d_in[0];
    const float* k = (const float*)d_in[1];
    const float* v = (const float*)d_in[2];
    float* out = (float*)d_out;

    const size_t MB = 1024ull * 1024ull;
    int S = 0;
    for (int s = 8; s >= 1; s >>= 1) {               // S=8: cache-healthy config
        size_t need = 4 * MB + (size_t)s * (4 * MB + 64 * 1024);
        if (ws_size >= need) { S = s; break; }
    }
    if (S == 0) {
        fa_naive<<<N_SEQ, 256, 0, stream>>>(q, k, v, out);
        return;
    }
    char* ws = (char*)d_ws;
    _Float16* K16s = (_Float16*)ws;
    _Float16* Vs   = (_Float16*)(ws + 2 * MB);
    float* Opart   = (float*)(ws + 4 * MB);
    float* lpart   = (float*)(ws + 4 * MB + (size_t)S * 4 * MB);
    float* mpart   = lpart + (size_t)S * N_SEQ;

    prep_kv<<<dim3(N_SEQ / 32), dim3(256), 0, stream>>>(k, v, K16s, Vs);
    fa_main<<<dim3(N_SEQ / 128, S), dim3(256), 0, stream>>>(q, K16s, Vs, Opart, lpart, mpart, (N_SEQ / 32) / S);
    fa_merge<<<dim3(N_SEQ / 64, HDIM / 32), dim3(256), 0, stream>>>(Opart, lpart, mpart, out, S);
}